// Round 1
// baseline (588.573 us; speedup 1.0000x reference)
//
#include <hip/hip_runtime.h>

typedef unsigned short us;
typedef short bf16x8 __attribute__((ext_vector_type(8)));
typedef short bf16x4 __attribute__((ext_vector_type(4)));
typedef float f32x4 __attribute__((ext_vector_type(4)));

#define MFMA16(a, b, c) __builtin_amdgcn_mfma_f32_16x16x32_bf16(a, b, c, 0, 0, 0)

typedef const unsigned int __attribute__((address_space(1)))* gp_t;
typedef unsigned int __attribute__((address_space(3)))* lp_t;

__device__ __forceinline__ void gload16(const void* g, void* l) {
  __builtin_amdgcn_global_load_lds((gp_t)g, (lp_t)l, 16, 0, 0);
}

__device__ __forceinline__ us f2bf(float f) {
  unsigned u = __float_as_uint(f);
  u += 0x7fffu + ((u >> 16) & 1u);
  return (us)(u >> 16);
}

// ---------------- convert fp32 -> bf16 (vectorized) ----------------
__global__ __launch_bounds__(256) void k_conv(const float* __restrict__ in,
                                              us* __restrict__ out, int n4) {
  int i = blockIdx.x * 256 + threadIdx.x;
  if (i >= n4) return;
  float4 f = reinterpret_cast<const float4*>(in)[i];
  ushort4 o;
  o.x = f2bf(f.x); o.y = f2bf(f.y); o.z = f2bf(f.z); o.w = f2bf(f.w);
  reinterpret_cast<ushort4*>(out)[i] = o;
}

// ---------------- transpose + convert W [K,N] f32 -> Wt [N,K] bf16 ----------------
__global__ __launch_bounds__(256) void k_transconv(const float* __restrict__ W,
                                                   us* __restrict__ Wt, int K, int N) {
  __shared__ float tile[32][33];
  int nbn = N >> 5;
  int kt = blockIdx.x / nbn, nt = blockIdx.x - kt * nbn;
  int tx = threadIdx.x & 31, ty = threadIdx.x >> 5;
#pragma unroll
  for (int j = 0; j < 4; ++j)
    tile[ty + 8 * j][tx] = W[(size_t)(kt * 32 + ty + 8 * j) * N + nt * 32 + tx];
  __syncthreads();
#pragma unroll
  for (int j = 0; j < 4; ++j)
    Wt[(size_t)(nt * 32 + ty + 8 * j) * K + kt * 32 + tx] = f2bf(tile[tx][ty + 8 * j]);
}

// ---------------- transpose V (bf16): [bh][2048][64] -> [bh][64][2048] ----------------
__global__ __launch_bounds__(256) void k_transv(const us* __restrict__ v,
                                                us* __restrict__ vT) {
  __shared__ us tile[32][33];
  int bh = blockIdx.x >> 7;       // 128 tiles per bh
  int tl = blockIdx.x & 127;
  int tt = tl >> 1, td = tl & 1;  // 64 t-tiles x 2 d-tiles
  int tx = threadIdx.x & 31, ty = threadIdx.x >> 5;
  const us* src = v + (size_t)bh * 2048 * 64;
  us* dst = vT + (size_t)bh * 64 * 2048;
#pragma unroll
  for (int j = 0; j < 4; ++j)
    tile[ty + 8 * j][tx] = src[(size_t)(tt * 32 + ty + 8 * j) * 64 + td * 32 + tx];
  __syncthreads();
#pragma unroll
  for (int j = 0; j < 4; ++j)
    dst[(size_t)(td * 32 + ty + 8 * j) * 2048 + tt * 32 + tx] = tile[tx][ty + 8 * j];
}

// ---------------- GEMM: A[M,K] bf16 x Bt[N,K] bf16 (m97 structure) ----------------
// EPI 0: qkv scatter into [B,H,T,Dh] (+bias). EPI 1: fp32 out (+bias).
template <int N, int EPI>
__global__ __launch_bounds__(256) void k_gemm(const us* __restrict__ A,
                                              const us* __restrict__ Bt,
                                              const float* __restrict__ bias,
                                              float* __restrict__ outf,
                                              us* __restrict__ qo, us* __restrict__ ko,
                                              us* __restrict__ vo) {
  constexpr int K = 1024;
  constexpr int NBN = N / 128;
  int bm = blockIdx.x / NBN, bn = blockIdx.x % NBN;
  int lane = threadIdx.x & 63, wv = threadIdx.x >> 6;
  int wm = wv >> 1, wn = wv & 1;
  int c = lane & 15, g = lane >> 4;
  int r4 = lane >> 2, c4 = lane & 3;

  __shared__ __attribute__((aligned(16))) us As[128 * 32];
  __shared__ __attribute__((aligned(16))) us Bs[128 * 32];

  f32x4 acc[4][4] = {};

  const us* Abase = A + (size_t)(bm * 128) * K;
  const us* Bbase = Bt + (size_t)(bn * 128) * K;

  for (int k0 = 0; k0 < K; k0 += 32) {
#pragma unroll
    for (int t = 0; t < 2; ++t) {
      int inst = wv * 2 + t;  // 0..7: 16 rows each, linear LDS dest
      gload16(Abase + (size_t)(inst * 16 + r4) * K + k0 + c4 * 8, As + inst * 512);
      gload16(Bbase + (size_t)(inst * 16 + r4) * K + k0 + c4 * 8, Bs + inst * 512);
    }
    __syncthreads();
    bf16x8 a[4], b[4];
#pragma unroll
    for (int m = 0; m < 4; ++m)
      a[m] = *reinterpret_cast<const bf16x8*>(&As[(wm * 64 + m * 16 + c) * 32 + g * 8]);
#pragma unroll
    for (int n = 0; n < 4; ++n)
      b[n] = *reinterpret_cast<const bf16x8*>(&Bs[(wn * 64 + n * 16 + c) * 32 + g * 8]);
#pragma unroll
    for (int m = 0; m < 4; ++m)
#pragma unroll
      for (int n = 0; n < 4; ++n) acc[m][n] = MFMA16(a[m], b[n], acc[m][n]);
    __syncthreads();
  }

#pragma unroll
  for (int m = 0; m < 4; ++m) {
#pragma unroll
    for (int n = 0; n < 4; ++n) {
#pragma unroll
      for (int i = 0; i < 4; ++i) {
        int gm = bm * 128 + wm * 64 + m * 16 + 4 * g + i;
        int gn = bn * 128 + wn * 64 + n * 16 + c;
        float val = acc[m][n][i] + bias[gn];
        if (EPI == 0) {
          int which = gn >> 10, cc = gn & 1023;
          int hh = cc >> 6, dd = cc & 63;
          int b_ = gm >> 11, t_ = gm & 2047;
          us* dst = (which == 0) ? qo : (which == 1) ? ko : vo;
          dst[(((size_t)b_ * 16 + hh) * 2048 + t_) * 64 + dd] = f2bf(val);
        } else {
          outf[(size_t)gm * N + gn] = val;
        }
      }
    }
  }
}

// ---------------- flash attention ----------------
// q,k: [bh][T][64] bf16; vT: [bh][64][T] bf16; y: [B*T][1024] bf16
__global__ __launch_bounds__(256) void k_attn(const us* __restrict__ qg,
                                              const us* __restrict__ kg,
                                              const us* __restrict__ vT,
                                              us* __restrict__ yb) {
  constexpr int T = 2048;
  constexpr float SCALE = 0.125f;          // 1/sqrt(64)
  constexpr float L2E = 1.44269504088896f; // log2(e)

  int qt = blockIdx.x & 31;   // q tile (64 rows)
  int bh = blockIdx.x >> 5;
  int b_ = bh >> 4, h = bh & 15;
  int lane = threadIdx.x & 63, wv = threadIdx.x >> 6;
  int c = lane & 15, g = lane >> 4;
  int q0 = qt * 64 + wv * 16;  // this wave's 16 q rows

  const us* Q = qg + ((size_t)bh * T + q0) * 64;
  const us* Kp = kg + (size_t)bh * T * 64;
  const us* Vp = vT + (size_t)bh * 64 * T;

  __shared__ __attribute__((aligned(16))) us Ps[4][16][72];  // per-wave P tile, padded

  bf16x8 qf[2];
#pragma unroll
  for (int ks = 0; ks < 2; ++ks)
    qf[ks] = *reinterpret_cast<const bf16x8*>(&Q[c * 64 + ks * 32 + g * 8]);

  f32x4 o[4] = {};
  float mrow[4], lrow[4];
#pragma unroll
  for (int i = 0; i < 4; ++i) { mrow[i] = -1e30f; lrow[i] = 0.f; }

  int ntiles = qt + 1;
  for (int j = 0; j < ntiles; ++j) {
    int j0 = j * 64;
    bool last = (j == ntiles - 1);
    f32x4 s[4] = {};
#pragma unroll
    for (int nf = 0; nf < 4; ++nf)
#pragma unroll
      for (int ks = 0; ks < 2; ++ks) {
        bf16x8 kf = *reinterpret_cast<const bf16x8*>(
            &Kp[(size_t)(j0 + nf * 16 + c) * 64 + ks * 32 + g * 8]);
        s[nf] = MFMA16(qf[ks], kf, s[nf]);
      }

#pragma unroll
    for (int i = 0; i < 4; ++i) {
      int qrow = q0 + 4 * g + i;
      float mx = -1e30f;
#pragma unroll
      for (int nf = 0; nf < 4; ++nf) {
        float sv = s[nf][i] * SCALE;
        if (last) {
          int kv = j0 + nf * 16 + c;
          sv = (kv <= qrow) ? sv : -1e30f;
        }
        s[nf][i] = sv;
        mx = fmaxf(mx, sv);
      }
#pragma unroll
      for (int d = 1; d < 16; d <<= 1) mx = fmaxf(mx, __shfl_xor(mx, d));
      float mnew = fmaxf(mrow[i], mx);
      float alpha = exp2f((mrow[i] - mnew) * L2E);
      mrow[i] = mnew;
      float rsum = 0.f;
#pragma unroll
      for (int nf = 0; nf < 4; ++nf) {
        float p = exp2f((s[nf][i] - mnew) * L2E);
        s[nf][i] = p;
        rsum += p;
      }
#pragma unroll
      for (int d = 1; d < 16; d <<= 1) rsum += __shfl_xor(rsum, d);
      lrow[i] = lrow[i] * alpha + rsum;
#pragma unroll
      for (int nf = 0; nf < 4; ++nf) o[nf][i] *= alpha;
#pragma unroll
      for (int nf = 0; nf < 4; ++nf)
        Ps[wv][4 * g + i][nf * 16 + c] = f2bf(s[nf][i]);
    }
    __syncthreads();  // wave-local ordering (per-wave buffers); uniform trip count

    bf16x8 pf[2];
#pragma unroll
    for (int ks = 0; ks < 2; ++ks) {
      bf16x4 lo = *reinterpret_cast<const bf16x4*>(&Ps[wv][c][ks * 32 + g * 8]);
      bf16x4 hi = *reinterpret_cast<const bf16x4*>(&Ps[wv][c][ks * 32 + g * 8 + 4]);
      pf[ks] = __builtin_shufflevector(lo, hi, 0, 1, 2, 3, 4, 5, 6, 7);
    }
#pragma unroll
    for (int nf = 0; nf < 4; ++nf)
#pragma unroll
      for (int ks = 0; ks < 2; ++ks) {
        bf16x8 vf = *reinterpret_cast<const bf16x8*>(
            &Vp[(size_t)(nf * 16 + c) * T + j0 + ks * 32 + g * 8]);
        o[nf] = MFMA16(pf[ks], vf, o[nf]);
      }
    __syncthreads();
  }

#pragma unroll
  for (int i = 0; i < 4; ++i) {
    float inv = 1.0f / lrow[i];
    int t_ = q0 + 4 * g + i;
    size_t base = ((size_t)b_ * T + t_) * 1024 + h * 64;
#pragma unroll
    for (int nf = 0; nf < 4; ++nf) yb[base + nf * 16 + c] = f2bf(o[nf][i] * inv);
  }
}

// ---------------- launcher ----------------
extern "C" void kernel_launch(void* const* d_in, const int* in_sizes, int n_in,
                              void* d_out, int out_size, void* d_ws, size_t ws_size,
                              hipStream_t stream) {
  (void)in_sizes; (void)n_in; (void)out_size; (void)ws_size;
  const float* x = (const float*)d_in[0];      // [4,2048,1024]
  const float* Wqkv = (const float*)d_in[1];   // [1024,3072]
  const float* bqkv = (const float*)d_in[2];   // [3072]
  const float* Wproj = (const float*)d_in[3];  // [1024,1024]
  const float* bproj = (const float*)d_in[4];  // [1024]
  float* out = (float*)d_out;                  // [4,2048,1024] f32

  char* ws = (char*)d_ws;
  us* xb = (us*)(ws);                    // 16 MB  [8192][1024]
  us* wqkvt = (us*)(ws + 16777216);      // 6 MB   [3072][1024]
  us* wprojt = (us*)(ws + 23068672);     // 2 MB   [1024][1024]
  us* qg = (us*)(ws + 25165824);         // 16 MB  [64][2048][64]
  us* kg = (us*)(ws + 41943040);         // 16 MB
  us* vT = (us*)(ws + 58720256);         // 16 MB  [64][64][2048]
  us* yb = (us*)(ws + 75497472);         // 16 MB  [8192][1024] (also vtmp)
  us* vtmp = yb;                         // v staging, consumed before yb written

  k_conv<<<8192, 256, 0, stream>>>(x, xb, 2097152);
  k_transconv<<<3072, 256, 0, stream>>>(Wqkv, wqkvt, 1024, 3072);
  k_transconv<<<1024, 256, 0, stream>>>(Wproj, wprojt, 1024, 1024);
  k_gemm<3072, 0><<<64 * 24, 256, 0, stream>>>(xb, wqkvt, bqkv, nullptr, qg, kg, vtmp);
  k_transv<<<64 * 128, 256, 0, stream>>>(vtmp, vT);
  k_attn<<<2048, 256, 0, stream>>>(qg, kg, vT, yb);
  k_gemm<1024, 1><<<64 * 8, 256, 0, stream>>>(yb, wprojt, bproj, out, nullptr, nullptr, nullptr);
}

// Round 2
// 245.917 us; speedup vs baseline: 2.3934x; 2.3934x over previous
//
#include <hip/hip_runtime.h>

typedef unsigned short us;
typedef short bf16x8 __attribute__((ext_vector_type(8)));
typedef short bf16x4 __attribute__((ext_vector_type(4)));
typedef float f32x4 __attribute__((ext_vector_type(4)));
typedef float f32x16 __attribute__((ext_vector_type(16)));
typedef int i32x4 __attribute__((ext_vector_type(4)));

#define MFMA16(a, b, c) __builtin_amdgcn_mfma_f32_16x16x32_bf16(a, b, c, 0, 0, 0)
#define MFMA32(a, b, c) __builtin_amdgcn_mfma_f32_32x32x16_bf16(a, b, c, 0, 0, 0)

typedef const unsigned int __attribute__((address_space(1)))* gp_t;
typedef unsigned int __attribute__((address_space(3)))* lp_t;

__device__ __forceinline__ void gload16(const void* g, void* l) {
  __builtin_amdgcn_global_load_lds((gp_t)g, (lp_t)l, 16, 0, 0);
}

__device__ __forceinline__ us f2bf(float f) {
  unsigned u = __float_as_uint(f);
  u += 0x7fffu + ((u >> 16) & 1u);
  return (us)(u >> 16);
}

__device__ __forceinline__ unsigned cvtpk(float lo, float hi) {
  unsigned r;
  asm("v_cvt_pk_bf16_f32 %0, %1, %2" : "=v"(r) : "v"(lo), "v"(hi));
  return r;
}

// ---------------- convert fp32 -> bf16 (vectorized) ----------------
__global__ __launch_bounds__(256) void k_conv(const float* __restrict__ in,
                                              us* __restrict__ out, int n4) {
  int i = blockIdx.x * 256 + threadIdx.x;
  if (i >= n4) return;
  float4 f = reinterpret_cast<const float4*>(in)[i];
  ushort4 o;
  o.x = f2bf(f.x); o.y = f2bf(f.y); o.z = f2bf(f.z); o.w = f2bf(f.w);
  reinterpret_cast<ushort4*>(out)[i] = o;
}

// ---------------- transpose + convert W [K,N] f32 -> Wt [N,K] bf16 ----------------
__global__ __launch_bounds__(256) void k_transconv(const float* __restrict__ W,
                                                   us* __restrict__ Wt, int K, int N) {
  __shared__ float tile[32][33];
  int nbn = N >> 5;
  int kt = blockIdx.x / nbn, nt = blockIdx.x - kt * nbn;
  int tx = threadIdx.x & 31, ty = threadIdx.x >> 5;
#pragma unroll
  for (int j = 0; j < 4; ++j)
    tile[ty + 8 * j][tx] = W[(size_t)(kt * 32 + ty + 8 * j) * N + nt * 32 + tx];
  __syncthreads();
#pragma unroll
  for (int j = 0; j < 4; ++j)
    Wt[(size_t)(nt * 32 + ty + 8 * j) * K + kt * 32 + tx] = f2bf(tile[tx][ty + 8 * j]);
}

// ---------------- transpose V (bf16): [bh][2048][64] -> [bh][64][2048] ----------------
__global__ __launch_bounds__(256) void k_transv(const us* __restrict__ v,
                                                us* __restrict__ vT) {
  __shared__ us tile[32][33];
  int bh = blockIdx.x >> 7;
  int tl = blockIdx.x & 127;
  int tt = tl >> 1, td = tl & 1;
  int tx = threadIdx.x & 31, ty = threadIdx.x >> 5;
  const us* src = v + (size_t)bh * 2048 * 64;
  us* dst = vT + (size_t)bh * 64 * 2048;
#pragma unroll
  for (int j = 0; j < 4; ++j)
    tile[ty + 8 * j][tx] = src[(size_t)(tt * 32 + ty + 8 * j) * 64 + td * 32 + tx];
  __syncthreads();
#pragma unroll
  for (int j = 0; j < 4; ++j)
    dst[(size_t)(td * 32 + ty + 8 * j) * 2048 + tt * 32 + tx] = tile[tx][ty + 8 * j];
}

// ---------------- GEMM: A[M,K] bf16 x Bt[N,K] bf16 (m97 structure) ----------------
// EPI 0: qkv scatter into [B,H,T,Dh] (+bias, q pre-scaled). EPI 1: fp32 out (+bias).
template <int N, int EPI>
__global__ __launch_bounds__(256) void k_gemm(const us* __restrict__ A,
                                              const us* __restrict__ Bt,
                                              const float* __restrict__ bias,
                                              float* __restrict__ outf,
                                              us* __restrict__ qo, us* __restrict__ ko,
                                              us* __restrict__ vo) {
  constexpr int K = 1024;
  constexpr int NBN = N / 128;
  constexpr float QSC = 0.125f * 1.44269504088896f;  // SCALE * log2(e) folded into q
  int bm = blockIdx.x / NBN, bn = blockIdx.x % NBN;
  int lane = threadIdx.x & 63, wv = threadIdx.x >> 6;
  int wm = wv >> 1, wn = wv & 1;
  int c = lane & 15, g = lane >> 4;
  int r4 = lane >> 2, c4 = lane & 3;

  __shared__ __attribute__((aligned(16))) us As[128 * 32];
  __shared__ __attribute__((aligned(16))) us Bs[128 * 32];

  f32x4 acc[4][4] = {};

  const us* Abase = A + (size_t)(bm * 128) * K;
  const us* Bbase = Bt + (size_t)(bn * 128) * K;

  for (int k0 = 0; k0 < K; k0 += 32) {
#pragma unroll
    for (int t = 0; t < 2; ++t) {
      int inst = wv * 2 + t;
      gload16(Abase + (size_t)(inst * 16 + r4) * K + k0 + c4 * 8, As + inst * 512);
      gload16(Bbase + (size_t)(inst * 16 + r4) * K + k0 + c4 * 8, Bs + inst * 512);
    }
    __syncthreads();
    bf16x8 a[4], b[4];
#pragma unroll
    for (int m = 0; m < 4; ++m)
      a[m] = *reinterpret_cast<const bf16x8*>(&As[(wm * 64 + m * 16 + c) * 32 + g * 8]);
#pragma unroll
    for (int n = 0; n < 4; ++n)
      b[n] = *reinterpret_cast<const bf16x8*>(&Bs[(wn * 64 + n * 16 + c) * 32 + g * 8]);
#pragma unroll
    for (int m = 0; m < 4; ++m)
#pragma unroll
      for (int n = 0; n < 4; ++n) acc[m][n] = MFMA16(a[m], b[n], acc[m][n]);
    __syncthreads();
  }

#pragma unroll
  for (int m = 0; m < 4; ++m) {
#pragma unroll
    for (int n = 0; n < 4; ++n) {
#pragma unroll
      for (int i = 0; i < 4; ++i) {
        int gm = bm * 128 + wm * 64 + m * 16 + 4 * g + i;
        int gn = bn * 128 + wn * 64 + n * 16 + c;
        float val = acc[m][n][i] + bias[gn];
        if (EPI == 0) {
          int which = gn >> 10, cc = gn & 1023;
          int hh = cc >> 6, dd = cc & 63;
          int b_ = gm >> 11, t_ = gm & 2047;
          us* dst = (which == 0) ? qo : (which == 1) ? ko : vo;
          float vv = (which == 0) ? val * QSC : val;
          dst[(((size_t)b_ * 16 + hh) * 2048 + t_) * 64 + dd] = f2bf(vv);
        } else {
          outf[(size_t)gm * N + gn] = val;
        }
      }
    }
  }
}

// ---------------- flash attention v2: swapped-operand 32x32, no LDS ----------------
// q (pre-scaled by SCALE*log2e), k: [bh][T][64] bf16; vT: [bh][64][T] bf16
// Each wave owns two 32-row q-slots (j, 63-j): exactly 33 KV tiles per wave.
// Block's 4 waves share the same KV-tile sequence (L1 reuse); XCD swizzle pins
// each bh's 8 blocks to one XCD so its 512 KB KV set stays in that L2.
__global__ __launch_bounds__(256) void k_attn2(const us* __restrict__ qg,
                                               const us* __restrict__ kg,
                                               const us* __restrict__ vT,
                                               us* __restrict__ yb) {
  constexpr int T = 2048;
  int lane = threadIdx.x & 63;
  int wv = threadIdx.x >> 6;
  int b = blockIdx.x;            // 512 blocks
  int x = b & 7, y = b >> 3;
  int bh = x * 8 + (y & 7);      // XCD x serves bh in [8x, 8x+8)
  int p = y >> 3;                // 0..7 -> qslot group
  int b_ = bh >> 4, hh = bh & 15;
  int c = lane & 31, h = lane >> 5;

  const us* Qb = qg + (size_t)bh * T * 64;
  const us* Kb = kg + (size_t)bh * T * 64;
  const us* Vb = vT + (size_t)bh * 64 * T;

#pragma unroll 1
  for (int pass = 0; pass < 2; ++pass) {
    int qslot = pass ? (63 - (4 * p + wv)) : (4 * p + wv);
    int q0 = qslot * 32;
    int qrow = q0 + c;
    int trip = (qslot >> 1) + 1;

    bf16x8 qf[4];
#pragma unroll
    for (int ks = 0; ks < 4; ++ks)
      qf[ks] = *reinterpret_cast<const bf16x8*>(&Qb[(size_t)qrow * 64 + ks * 16 + h * 8]);

    f32x16 o0 = {}, o1 = {};
    float m = -1e30f, lsum = 0.f;

    for (int j = 0; j < trip; ++j) {
      int j0 = j * 64;
      // ---- QK^T swapped: S^T[k_local][q] ----
      f32x16 sA = {}, sB = {};
#pragma unroll
      for (int ks = 0; ks < 4; ++ks) {
        bf16x8 kfA = *reinterpret_cast<const bf16x8*>(
            &Kb[(size_t)(j0 + c) * 64 + ks * 16 + h * 8]);
        bf16x8 kfB = *reinterpret_cast<const bf16x8*>(
            &Kb[(size_t)(j0 + 32 + c) * 64 + ks * 16 + h * 8]);
        sA = MFMA32(kfA, qf[ks], sA);
        sB = MFMA32(kfB, qf[ks], sB);
      }
      // ---- causal mask (last tile only, contains the diagonal) ----
      if (j == trip - 1) {
#pragma unroll
        for (int r = 0; r < 16; ++r) {
          int kl = j0 + (r & 3) + 8 * (r >> 2) + 4 * h;
          if (kl > qrow) sA[r] = -1e30f;
          if (kl + 32 > qrow) sB[r] = -1e30f;
        }
      }
      // ---- online softmax: lane owns column q = q0+c (both halves identical) ----
      float mx = -1e30f;
#pragma unroll
      for (int r = 0; r < 16; ++r) mx = fmaxf(mx, fmaxf(sA[r], sB[r]));
      mx = fmaxf(mx, __shfl_xor(mx, 32));
      if (!__all(mx <= m)) {  // defer-rescale (exact: skip when max unchanged)
        float mnew = fmaxf(m, mx);
        float alpha = __builtin_amdgcn_exp2f(m - mnew);
        m = mnew;
        lsum *= alpha;
#pragma unroll
        for (int r = 0; r < 16; ++r) { o0[r] *= alpha; o1[r] *= alpha; }
      }
      float rs = 0.f;
#pragma unroll
      for (int r = 0; r < 16; ++r) {
        sA[r] = __builtin_amdgcn_exp2f(sA[r] - m);
        sB[r] = __builtin_amdgcn_exp2f(sB[r] - m);
        rs += sA[r] + sB[r];
      }
      rs += __shfl_xor(rs, 32);
      lsum += rs;

      // ---- P -> bf16 B-fragments (cvt_pk + lane^32 exchange), PV swapped ----
#pragma unroll
      for (int half = 0; half < 2; ++half) {
#pragma unroll
        for (int b2 = 0; b2 < 2; ++b2) {
          int base = 8 * b2;
          unsigned w0, w1, w2, w3;
          if (half == 0) {
            w0 = cvtpk(sA[base + 0], sA[base + 1]);
            w1 = cvtpk(sA[base + 2], sA[base + 3]);
            w2 = cvtpk(sA[base + 4], sA[base + 5]);
            w3 = cvtpk(sA[base + 6], sA[base + 7]);
          } else {
            w0 = cvtpk(sB[base + 0], sB[base + 1]);
            w1 = cvtpk(sB[base + 2], sB[base + 3]);
            w2 = cvtpk(sB[base + 4], sB[base + 5]);
            w3 = cvtpk(sB[base + 6], sB[base + 7]);
          }
          unsigned pw0 = (unsigned)__shfl_xor((int)w0, 32);
          unsigned pw1 = (unsigned)__shfl_xor((int)w1, 32);
          unsigned pw2 = (unsigned)__shfl_xor((int)w2, 32);
          unsigned pw3 = (unsigned)__shfl_xor((int)w3, 32);
          i32x4 pi;
          pi[0] = (int)(h ? pw2 : w0);
          pi[1] = (int)(h ? pw3 : w1);
          pi[2] = (int)(h ? w2 : pw0);
          pi[3] = (int)(h ? w3 : pw1);
          bf16x8 pa = __builtin_bit_cast(bf16x8, pi);
          int kb = j0 + (half * 2 + b2) * 16 + h * 8;
          bf16x8 vf0 = *reinterpret_cast<const bf16x8*>(&Vb[(size_t)c * T + kb]);
          bf16x8 vf1 = *reinterpret_cast<const bf16x8*>(&Vb[(size_t)(32 + c) * T + kb]);
          o0 = MFMA32(vf0, pa, o0);  // O^T[d 0..31][q]
          o1 = MFMA32(vf1, pa, o1);  // O^T[d 32..63][q]
        }
      }
    }

    // ---- epilogue: O^T lane holds q=q0+c col; d = crow(r,h) rows ----
    float inv = 1.0f / lsum;
    size_t ob = ((size_t)b_ * T + qrow) * 1024 + (size_t)hh * 64;
#pragma unroll
    for (int r = 0; r < 16; r += 2) {
      int d = (r & 3) + 8 * (r >> 2) + 4 * h;
      *reinterpret_cast<unsigned*>(&yb[ob + d]) = cvtpk(o0[r] * inv, o0[r + 1] * inv);
      *reinterpret_cast<unsigned*>(&yb[ob + 32 + d]) = cvtpk(o1[r] * inv, o1[r + 1] * inv);
    }
  }
}

// ---------------- launcher ----------------
extern "C" void kernel_launch(void* const* d_in, const int* in_sizes, int n_in,
                              void* d_out, int out_size, void* d_ws, size_t ws_size,
                              hipStream_t stream) {
  (void)in_sizes; (void)n_in; (void)out_size; (void)ws_size;
  const float* x = (const float*)d_in[0];      // [4,2048,1024]
  const float* Wqkv = (const float*)d_in[1];   // [1024,3072]
  const float* bqkv = (const float*)d_in[2];   // [3072]
  const float* Wproj = (const float*)d_in[3];  // [1024,1024]
  const float* bproj = (const float*)d_in[4];  // [1024]
  float* out = (float*)d_out;                  // [4,2048,1024] f32

  char* ws = (char*)d_ws;
  us* xb = (us*)(ws);                    // 16 MB  [8192][1024]
  us* wqkvt = (us*)(ws + 16777216);      // 6 MB   [3072][1024]
  us* wprojt = (us*)(ws + 23068672);     // 2 MB   [1024][1024]
  us* qg = (us*)(ws + 25165824);         // 16 MB  [64][2048][64] (pre-scaled)
  us* kg = (us*)(ws + 41943040);         // 16 MB
  us* vT = (us*)(ws + 58720256);         // 16 MB  [64][64][2048]
  us* yb = (us*)(ws + 75497472);         // 16 MB  [8192][1024] (also vtmp)
  us* vtmp = yb;                         // v staging, consumed before yb written

  k_conv<<<8192, 256, 0, stream>>>(x, xb, 2097152);
  k_transconv<<<3072, 256, 0, stream>>>(Wqkv, wqkvt, 1024, 3072);
  k_transconv<<<1024, 256, 0, stream>>>(Wproj, wprojt, 1024, 1024);
  k_gemm<3072, 0><<<64 * 24, 256, 0, stream>>>(xb, wqkvt, bqkv, nullptr, qg, kg, vtmp);
  k_transv<<<64 * 128, 256, 0, stream>>>(vtmp, vT);
  k_attn2<<<512, 256, 0, stream>>>(qg, kg, vT, yb);
  k_gemm<1024, 1><<<64 * 8, 256, 0, stream>>>(yb, wprojt, bproj, out, nullptr, nullptr, nullptr);
}